// Round 3
// baseline (246.610 us; speedup 1.0000x reference)
//
#include <hip/hip_runtime.h>
#include <hip/hip_bf16.h>
#include <hip/hip_fp16.h>
#include <math.h>

#define NN 64
#define DD 128
#define PP 4800
#define KK 64
#define BPN 15          // blocks per sample n
#define PB  320         // positions per block
#define CP  64          // positions per chunk
#define NCH 5           // chunks per block

#define TSTR 72         // tile stride in halfwords (4x16 bf16 subtile + 8 pad)

// ws element offsets
#define PAGG_SZ  ((size_t)NN * BPN * KK * DD)   // element count; fp16 (15.7 MB)
#define PSSUM_SZ ((size_t)NN * BPN * KK)

typedef __attribute__((ext_vector_type(8))) short bf16x8;
typedef __attribute__((ext_vector_type(4))) float f32x4;
typedef __attribute__((ext_vector_type(2))) unsigned int u32x2;
typedef __attribute__((address_space(3))) const unsigned short lds_cus;

__device__ __forceinline__ unsigned pk2(float a, float b) {
  union { __hip_bfloat162 h2; unsigned u; } cv;
  cv.h2 = __float22bfloat162_rn(make_float2(a, b));  // low = a, high = b
  return cv.u;
}

// hw transpose read: 16-lane group; lane g supplies tile_base + 8g bytes,
// lane l receives elems j=0..3 = lds_hw[tile_base_hw + 16j + (l&15)]
#define TR_READ(dst, addr, imm)                                          \
  asm volatile("ds_read_b64_tr_b16 %0, %1 offset:" #imm                  \
               : "=v"(dst) : "v"(addr))

// ---------------------------------------------------------------------------
// Fused main. x staged ONCE in d-major 4x16-subtiled bf16 (tile T(d,p) =
// (d>>2)*4 + (p>>4), elem (d&3)*16 + (p&15)); GEMM1 B via tr-reads.
// This round: W in registers (no w_s LDS), sa in [p][k] 4x16-subtiled LDS
// (b64 stores + tr-read A-frags for GEMM2), no-max softmax, DPP-based ssq
// reduce with per-wave slabs (no LDS atomics). LDS 46KB -> 28.7KB.
// ---------------------------------------------------------------------------
__global__ __launch_bounds__(256, 2) void main_kernel(const float* __restrict__ x,
                                                      const float* __restrict__ conv_w,
                                                      __half* __restrict__ pagg,
                                                      float* __restrict__ pssum) {
  __shared__ __align__(16) unsigned short xdp[128 * TSTR];  // 18432 B (x tiled)
  __shared__ __align__(16) unsigned short sa_t[64 * TSTR];  //  9216 B (sa tiled [p][k])
  __shared__ float red_s[256];  // ssq: [wv][64] per-wave slabs; flush: 256 partials

  const int b = blockIdx.x;
  const int n = b / BPN, sl = b % BPN;
  const int t = threadIdx.x, lane = t & 63, wv = t >> 6;
  const int lq = lane >> 4, ll = lane & 15;
  const int pb = t & 7, db = t >> 3;  // staging tile: p in [8pb,8pb+8), d in [4db,4db+4)

  // ---- W fragments -> registers (once; W is 32KB, L2/L3-hot, wv-independent)
  bf16x8 wf[4][4];
#pragma unroll
  for (int kt = 0; kt < 4; ++kt)
#pragma unroll
    for (int ks = 0; ks < 4; ++ks) {
      const float* wp = conv_w + (kt * 16 + ll) * DD + ks * 32 + lq * 8;
      float4 a = *(const float4*)wp;
      float4 c = *(const float4*)(wp + 4);
      union { unsigned u[4]; bf16x8 v; } cv;
      cv.u[0] = pk2(a.x, a.y); cv.u[1] = pk2(a.z, a.w);
      cv.u[2] = pk2(c.x, c.y); cv.u[3] = pk2(c.z, c.w);
      wf[kt][ks] = cv.v;
    }

  const float* xb = x + (size_t)n * DD * PP + (size_t)(4 * db) * PP + sl * PB + 8 * pb;

  float4 pf[8];
#pragma unroll
  for (int r = 0; r < 4; ++r) {
    pf[2 * r]     = *(const float4*)(xb + (size_t)r * PP);
    pf[2 * r + 1] = *(const float4*)(xb + (size_t)r * PP + 4);
  }

  f32x4 acc[8];
#pragma unroll
  for (int i = 0; i < 8; ++i) acc[i] = (f32x4){0.f, 0.f, 0.f, 0.f};
  float ssacc[16];
#pragma unroll
  for (int i = 0; i < 16; ++i) ssacc[i] = 0.f;

  // staging write base: thread covers tile Tw = db*4 + (pb>>1), cols 8*(pb&1)..+8
  const int wbase = (db * 4 + (pb >> 1)) * TSTR + 8 * (pb & 1);
  // GEMM1 tr-read base: tile (8lq+wv) of xdp, lane ll supplies 8B at +8*ll
  const unsigned trbase =
      (unsigned)(size_t)((lds_cus*)xdp + (8 * lq + wv) * TSTR + 4 * ll);
  // GEMM2 A tr-read base: tile (8lq+wv)? -> T=(8ks+2lq)*4+wv => base tile (2lq*4+wv)
  const unsigned atrbase =
      (unsigned)(size_t)((lds_cus*)sa_t + (8 * lq + wv) * TSTR + 4 * ll);
  // GEMM2 B b128 base (halfwords)
  const int g2base = ((ll >> 2) * 4 + (lq >> 1)) * TSTR + (ll & 3) * 16 + (lq & 1) * 8;
  const int prow_ = wv * 16 + ll;
  // sa_t store base (halfwords): T0=(prow>>2)*4, within-tile (prow&3)*16 + lq*4
  const int sabase = ((prow_ >> 2) * 4) * TSTR + (prow_ & 3) * 16 + lq * 4;

  for (int c = 0; c < NCH; ++c) {
    float4 cur[8];
#pragma unroll
    for (int i = 0; i < 8; ++i) cur[i] = pf[i];
    if (c + 1 < NCH) {  // prefetch next chunk; completes during this chunk's compute
      const float* xc = xb + (c + 1) * CP;
#pragma unroll
      for (int r = 0; r < 4; ++r) {
        pf[2 * r]     = *(const float4*)(xc + (size_t)r * PP);
        pf[2 * r + 1] = *(const float4*)(xc + (size_t)r * PP + 4);
      }
    }

    // ---- fp32 per-p partial sum-of-squares over this thread's 4 d-rows
    float sq[8];
#pragma unroll
    for (int h = 0; h < 2; ++h)
#pragma unroll
      for (int j = 0; j < 4; ++j) {
        float s = 0.f;
#pragma unroll
        for (int r = 0; r < 4; ++r) {
          float v = (&cur[2 * r + h].x)[j];
          s = fmaf(v, v, s);
        }
        sq[4 * h + j] = s;
      }
    // lane^8 via DPP row_ror:8 (VALU pipe, not DS)
#pragma unroll
    for (int i = 0; i < 8; ++i) {
      int d = __builtin_amdgcn_update_dpp(0, __float_as_int(sq[i]), 0x128, 0xF, 0xF, false);
      sq[i] += __int_as_float(d);
    }
    // fold 8 -> 4 values using the lane^8 duplication
    float v4[4];
#pragma unroll
    for (int j = 0; j < 4; ++j) v4[j] = (lane & 8) ? sq[j + 4] : sq[j];
#pragma unroll
    for (int j = 0; j < 4; ++j) {  // reduce db bits 1,2
      v4[j] += __shfl_xor(v4[j], 16);
      v4[j] += __shfl_xor(v4[j], 32);
    }

    __syncthreads();  // xdp/sa_t free (prev GEMM2 done)

    if (lane < 16) {  // per-wave ssq slab, plain b128 write (no atomics, no zeroing)
      float4 o = {v4[0], v4[1], v4[2], v4[3]};
      *(float4*)&red_s[wv * 64 + 8 * (lane & 7) + 4 * (lane >> 3)] = o;
    }

    // ---- convert + stage into tiled xdp: 4x b128 per thread, subtile rows
#pragma unroll
    for (int r = 0; r < 4; ++r) {
      const float4& a = cur[2 * r];
      const float4& c2 = cur[2 * r + 1];
      uint4 o = {pk2(a.x, a.y), pk2(a.z, a.w), pk2(c2.x, c2.y), pk2(c2.z, c2.w)};
      *(uint4*)&xdp[wbase + r * 16] = o;
    }
    __syncthreads();  // staging + ssq visible

    // ---- GEMM1 (logits, A from registers) + no-max softmax over K=64
    {
      u32x2 trv[8];
      TR_READ(trv[0], trbase, 0);
      TR_READ(trv[1], trbase, 576);
      TR_READ(trv[2], trbase, 4608);
      TR_READ(trv[3], trbase, 5184);
      TR_READ(trv[4], trbase, 9216);
      TR_READ(trv[5], trbase, 9792);
      TR_READ(trv[6], trbase, 13824);
      TR_READ(trv[7], trbase, 14400);
      asm volatile("s_waitcnt lgkmcnt(0)" ::: "memory");
      __builtin_amdgcn_sched_barrier(0);

      f32x4 lg[4];
#pragma unroll
      for (int kt = 0; kt < 4; ++kt) lg[kt] = (f32x4){0.f, 0.f, 0.f, 0.f};
#pragma unroll
      for (int ks = 0; ks < 4; ++ks) {
        union { unsigned u[4]; bf16x8 v; } bu;
        bu.u[0] = trv[2 * ks].x;
        bu.u[1] = trv[2 * ks].y;
        bu.u[2] = trv[2 * ks + 1].x;
        bu.u[3] = trv[2 * ks + 1].y;
        bf16x8 bfrag = bu.v;
#pragma unroll
        for (int kt = 0; kt < 4; ++kt)
          lg[kt] = __builtin_amdgcn_mfma_f32_16x16x32_bf16(wf[kt][ks], bfrag, lg[kt], 0, 0, 0);
      }
      // ssq: sum the 4 per-wave slabs
      float sum4 = red_s[prow_] + red_s[64 + prow_] + red_s[128 + prow_] + red_s[192 + prow_];
      float iv = 1.0f / fmaxf(sqrtf(sum4), 1e-12f);
      // |logit*iv| <= ~1.4 (||0.1*N(0,1)_128|| ~= 1.13): exp safe without max-sub
      float vals[16];
#pragma unroll
      for (int kt = 0; kt < 4; ++kt)
#pragma unroll
        for (int r = 0; r < 4; ++r)
          vals[kt * 4 + r] = __expf(lg[kt][r] * iv);
      // tree sum (depth 4)
      float s0 = (vals[0] + vals[1]) + (vals[2] + vals[3]);
      float s1 = (vals[4] + vals[5]) + (vals[6] + vals[7]);
      float s2 = (vals[8] + vals[9]) + (vals[10] + vals[11]);
      float s3 = (vals[12] + vals[13]) + (vals[14] + vals[15]);
      float se = (s0 + s1) + (s2 + s3);
      se += __shfl_xor(se, 16);
      se += __shfl_xor(se, 32);
      float rinv = 1.0f / se;
      float r2 = rinv * iv;  // fold invn into sa for GEMM2
#pragma unroll
      for (int kt = 0; kt < 4; ++kt) {
        float e0 = vals[kt * 4 + 0], e1 = vals[kt * 4 + 1];
        float e2 = vals[kt * 4 + 2], e3 = vals[kt * 4 + 3];
        ssacc[kt * 4 + 0] += e0 * rinv;
        ssacc[kt * 4 + 1] += e1 * rinv;
        ssacc[kt * 4 + 2] += e2 * rinv;
        ssacc[kt * 4 + 3] += e3 * rinv;
        // sa_t[p][k] tiled store: one b64 per kt (k = kt*16 + lq*4 + 0..3)
        *(uint2*)&sa_t[sabase + kt * TSTR] =
            make_uint2(pk2(e0 * r2, e1 * r2), pk2(e2 * r2, e3 * r2));
      }
    }
    __syncthreads();  // sa_t visible

    // ---- GEMM2: acc[k-tile = wv][dt] += SA * X^T (A via tr-reads, B b128)
    {
      u32x2 av[4];
      TR_READ(av[0], atrbase, 0);
      TR_READ(av[1], atrbase, 576);
      TR_READ(av[2], atrbase, 4608);
      TR_READ(av[3], atrbase, 5184);
      asm volatile("s_waitcnt lgkmcnt(0)" ::: "memory");
      __builtin_amdgcn_sched_barrier(0);
#pragma unroll
      for (int ks = 0; ks < 2; ++ks) {
        union { unsigned u[4]; bf16x8 v; } au;
        au.u[0] = av[2 * ks].x;
        au.u[1] = av[2 * ks].y;
        au.u[2] = av[2 * ks + 1].x;
        au.u[3] = av[2 * ks + 1].y;
        bf16x8 afrag = au.v;
#pragma unroll
        for (int dt = 0; dt < 8; ++dt) {
          bf16x8 bfrag = *(const bf16x8*)&xdp[g2base + dt * (16 * TSTR) + ks * (2 * TSTR)];
          acc[dt] = __builtin_amdgcn_mfma_f32_16x16x32_bf16(afrag, bfrag, acc[dt], 0, 0, 0);
        }
      }
    }
  }

  // ---- flush agg partial slab as fp16 (C-layout: k = 16wv+4lq+r, d = 16dt+ll)
  {
    __half* base = pagg + (size_t)(n * BPN + sl) * (KK * DD);
#pragma unroll
    for (int dt = 0; dt < 8; ++dt)
#pragma unroll
      for (int r = 0; r < 4; ++r)
        base[(16 * wv + 4 * lq + r) * DD + dt * 16 + ll] = __float2half(acc[dt][r]);
  }
  // ---- flush ssum (fp32)
#pragma unroll
  for (int i = 0; i < 16; ++i) {
    float s = ssacc[i];
    s += __shfl_xor(s, 1);
    s += __shfl_xor(s, 2);
    s += __shfl_xor(s, 4);
    s += __shfl_xor(s, 8);
    if (ll == 0) red_s[wv * 64 + (i >> 2) * 16 + lq * 4 + (i & 3)] = s;
  }
  __syncthreads();
  if (t < 64)
    pssum[(n * BPN + sl) * KK + t] =
        red_s[t] + red_s[64 + t] + red_s[128 + t] + red_s[192 + t];
}

// ---------------------------------------------------------------------------
// Fused epilogue (512 blocks): reduce 15 fp16 slabs, vlad = agg - ssum*cent,
// intra-normalize per k, then the ANALYTIC global norm (||vlad||=sqrt(64)=8
// after intra-norm since every k-row is unit) -> *0.125, store to out.
// ---------------------------------------------------------------------------
__global__ __launch_bounds__(256) void ep_kernel(const __half* __restrict__ pagg,
                                                 const float* __restrict__ pssum,
                                                 const float* __restrict__ cent,
                                                 float* __restrict__ out) {
  const int blk = blockIdx.x;
  const int n = blk >> 3, kg = blk & 7;
  const int t = threadIdx.x;
  const int kl = t >> 5, c32 = t & 31;  // k-row in block, 32 lanes per row
  const int k = kg * 8 + kl;
  const size_t off = (size_t)k * DD + c32 * 4;

  const __half* base = pagg + (size_t)n * BPN * (KK * DD) + off;
  float4 a = {0.f, 0.f, 0.f, 0.f};
  for (int s = 0; s < BPN; ++s) {
    uint2 u = *(const uint2*)(base + (size_t)s * (KK * DD));
    __half2 h0 = *(const __half2*)&u.x;
    __half2 h1 = *(const __half2*)&u.y;
    float2 f0 = __half22float2(h0);
    float2 f1 = __half22float2(h1);
    a.x += f0.x; a.y += f0.y; a.z += f1.x; a.w += f1.y;
  }
  float sk = 0.f;
  for (int s = 0; s < BPN; ++s) sk += pssum[(n * BPN + s) * KK + k];

  float4 c4 = *(const float4*)(cent + off);
  float4 v;
  v.x = fmaf(-sk, c4.x, a.x);
  v.y = fmaf(-sk, c4.y, a.y);
  v.z = fmaf(-sk, c4.z, a.z);
  v.w = fmaf(-sk, c4.w, a.w);

  float ss = v.x * v.x + v.y * v.y + v.z * v.z + v.w * v.w;
  ss += __shfl_xor(ss, 1);
  ss += __shfl_xor(ss, 2);
  ss += __shfl_xor(ss, 4);
  ss += __shfl_xor(ss, 8);
  ss += __shfl_xor(ss, 16);  // row total (32 lanes per k-row)
  float scale = 0.125f / fmaxf(sqrtf(ss), 1e-12f);  // intra-norm * global 1/sqrt(64)
  v.x *= scale; v.y *= scale; v.z *= scale; v.w *= scale;
  *(float4*)(out + (size_t)n * (KK * DD) + off) = v;
}

extern "C" void kernel_launch(void* const* d_in, const int* in_sizes, int n_in,
                              void* d_out, int out_size, void* d_ws, size_t ws_size,
                              hipStream_t stream) {
  const float* x      = (const float*)d_in[0];
  const float* conv_w = (const float*)d_in[1];
  const float* cent   = (const float*)d_in[2];
  float* out = (float*)d_out;
  float* ws  = (float*)d_ws;

  __half* pagg = (__half*)ws;                 // PAGG_SZ halves = 15.7 MB
  float* pssum = ws + PAGG_SZ / 2;            // fp32, after the fp16 slab region

  main_kernel<<<NN * BPN, 256, 0, stream>>>(x, conv_w, pagg, pssum);
  ep_kernel<<<NN * 8, 256, 0, stream>>>(pagg, pssum, cent, out);
}